// Round 6
// baseline (318.018 us; speedup 1.0000x reference)
//
#include <hip/hip_runtime.h>

#pragma clang fp contract(off)

#define N_ANCH 321408
#define NQUAD (N_ANCH / 4)
#define KSEL 4096
#define POST 300
#define H1BINS 1024
#define H1BASE 0x3D40u   // remap: bin = (k>>16) - H1BASE + 1 ; bin 0 = invalid (k==0)
#define CANDCAP 16384

typedef unsigned int u32;
typedef unsigned long long u64;

__device__ __forceinline__ u32 key_of(float m) {
    float s = 1.0f / (1.0f + expf(-m));
    return (s >= 0.05f) ? __float_as_uint(s) : 0u;
}

// ---------------- scoring (vectorized 4 anchors/thread) + coarse histogram ----------------
__global__ __launch_bounds__(1024) void k_keys(const float4* __restrict__ cls4,
                                               uint4* __restrict__ keys4,
                                               u32* __restrict__ hist) {
    __shared__ u32 h0[H1BINS], h1[H1BINS];
    int t = threadIdx.x;
    h0[t] = 0; h1[t] = 0;
    __syncthreads();
    int q = blockIdx.x * 1024 + t;
    if (q < NQUAD) {
        float4 a = cls4[q * 3], b = cls4[q * 3 + 1], d = cls4[q * 3 + 2];
        u32 k0 = key_of(fmaxf(a.x, fmaxf(a.y, a.z)));
        u32 k1 = key_of(fmaxf(a.w, fmaxf(b.x, b.y)));
        u32 k2 = key_of(fmaxf(b.z, fmaxf(b.w, d.x)));
        u32 k3 = key_of(fmaxf(d.y, fmaxf(d.z, d.w)));
        keys4[q] = make_uint4(k0, k1, k2, k3);
        u32* hp = (t & 1) ? h1 : h0;
        atomicAdd(&hp[k0 ? ((k0 >> 16) - H1BASE + 1u) : 0u], 1u);
        atomicAdd(&hp[k1 ? ((k1 >> 16) - H1BASE + 1u) : 0u], 1u);
        atomicAdd(&hp[k2 ? ((k2 >> 16) - H1BASE + 1u) : 0u], 1u);
        atomicAdd(&hp[k3 ? ((k3 >> 16) - H1BASE + 1u) : 0u], 1u);
    }
    __syncthreads();
    u32 c = h0[t] + h1[t];
    if (c) atomicAdd(&hist[t], c);
}

// scan 1024 coarse bins from the top: crossing bin + total valid count
__global__ __launch_bounds__(1024) void k_scan1(const u32* __restrict__ hist, u32* scal) {
    __shared__ u32 sh[1024];
    int t = threadIdx.x;
    int b = 1023 - t;                 // descending bins
    u32 s = hist[b];
    sh[t] = s;
    __syncthreads();
    for (int off = 1; off < 1024; off <<= 1) {
        u32 x = sh[t];
        u32 y = (t >= off) ? sh[t - off] : 0u;
        __syncthreads();
        sh[t] = x + y;
        __syncthreads();
    }
    u32 incl = sh[t];
    u32 excl = incl - s;
    if (excl < 4096u && incl >= 4096u) {
        scal[8] = (b > 0) ? (u32)(b - 1) + H1BASE : 0u;   // actual upper-16 of crossing bin
    }
    if (t == 1023) scal[9] = incl - s;                    // total valid (minus bin 0)
}

// all candidates in bins >= crossing bin; wave-aggregated atomic, vectorized reads
__global__ __launch_bounds__(256) void k_compact(const uint4* __restrict__ keys4,
                                                 u32* scal, u64* __restrict__ cand) {
    int q = blockIdx.x * 256 + threadIdx.x;
    bool act = q < NQUAD;
    uint4 kv = act ? keys4[q] : make_uint4(0, 0, 0, 0);
    u32 thr16 = scal[8];
    int lane = threadIdx.x & 63;
    u32 i0 = (u32)q * 4u;
    bool p0 = kv.x && (kv.x >> 16) >= thr16;
    bool p1 = kv.y && (kv.y >> 16) >= thr16;
    bool p2 = kv.z && (kv.z >> 16) >= thr16;
    bool p3 = kv.w && (kv.w >> 16) >= thr16;
    u64 b0 = __ballot(p0), b1 = __ballot(p1), b2 = __ballot(p2), b3 = __ballot(p3);
    u32 n0 = (u32)__popcll(b0), n1 = (u32)__popcll(b1), n2 = (u32)__popcll(b2);
    u32 nw = n0 + n1 + n2 + (u32)__popcll(b3);
    u32 base = 0;
    if (lane == 0 && nw) base = atomicAdd(&scal[5], nw);
    base = (u32)__shfl((int)base, 0);
    u64 lt = (lane == 0) ? 0ull : (~0ull >> (64 - lane));
    if (p0) { u32 p = base + (u32)__popcll(b0 & lt);
              if (p < CANDCAP) cand[p] = (((u64)kv.x) << 32) | (u32)(~(i0 + 0)); }
    if (p1) { u32 p = base + n0 + (u32)__popcll(b1 & lt);
              if (p < CANDCAP) cand[p] = (((u64)kv.y) << 32) | (u32)(~(i0 + 1)); }
    if (p2) { u32 p = base + n0 + n1 + (u32)__popcll(b2 & lt);
              if (p < CANDCAP) cand[p] = (((u64)kv.z) << 32) | (u32)(~(i0 + 2)); }
    if (p3) { u32 p = base + n0 + n1 + n2 + (u32)__popcll(b3 & lt);
              if (p < CANDCAP) cand[p] = (((u64)kv.w) << 32) | (u32)(~(i0 + 3)); }
}

// 2D partial rank-by-counting
__global__ __launch_bounds__(256) void k_rankpart(const u32* __restrict__ scal,
                                                  const u64* __restrict__ cand,
                                                  u32* __restrict__ rank) {
    __shared__ u64 ch[512];
    u32 nc = scal[5]; if (nc > CANDCAP) nc = CANDCAP;
    u32 cb = blockIdx.x * 256u;
    u32 jb = blockIdx.y * 512u;
    if (cb >= nc || jb >= nc) return;
    u32 t = threadIdx.x;
    for (u32 j = t; j < 512u; j += 256u)
        ch[j] = (jb + j < nc) ? cand[jb + j] : 0ull;
    __syncthreads();
    u32 me = cb + t;
    u64 mine = (me < nc) ? cand[me] : ~0ull;
    u32 r = 0;
    #pragma unroll 8
    for (int j = 0; j < 512; ++j) r += (ch[j] > mine) ? 1u : 0u;
    if (me < nc && r) atomicAdd(&rank[me], r);
}

__global__ void k_scatter(const u32* __restrict__ scal, const u64* __restrict__ cand,
                          const u32* __restrict__ rank, u64* __restrict__ sorted) {
    u32 nc = scal[5]; if (nc > CANDCAP) nc = CANDCAP;
    u32 t = blockIdx.x * 256u + threadIdx.x;
    if (t < nc) {
        u32 r = rank[t];
        if (r < (u32)KSEL) sorted[r] = cand[t];
    }
}

// ---------------- decode helpers ----------
__device__ __forceinline__ void decode_box(u64 cpack, const float* __restrict__ boxp,
                                           const float* __restrict__ anch, float b[7]) {
    u32 key = (u32)(cpack >> 32);
    u32 idx = ~((u32)(cpack & 0xFFFFFFFFull));
    if (key == 0u) idx = 0u;
    const float* a7 = anch + (size_t)idx * 7;
    const float* t7 = boxp + (size_t)idx * 7;
    float xa = a7[0], ya = a7[1], za = a7[2], wa = a7[3], la = a7[4], ha = a7[5], ra = a7[6];
    float xt = t7[0], yt = t7[1], zt = t7[2], wt = t7[3], lt_ = t7[4], ht = t7[5], rt = t7[6];
    za = za + ha * 0.5f;
    float diag = sqrtf(la * la + wa * wa);
    float xg = xt * diag + xa;
    float yg = yt * diag + ya;
    float zg = zt * ha + za;
    float lg = expf(lt_) * la;
    float wg = expf(wt) * wa;
    float hg = expf(ht) * ha;
    float rg = rt + ra;
    zg = zg - hg * 0.5f;
    b[0] = xg; b[1] = yg; b[2] = zg; b[3] = wg; b[4] = lg; b[5] = hg; b[6] = rg;
}

__device__ __forceinline__ float4 standup_box(const float b[7], float* areao) {
    float xg = b[0], yg = b[1], wg = b[3], lg = b[4], rg = b[6];
    float cc = cosf(rg), ss = sinf(rg);
    float dx = wg * 0.5f, dy = lg * 0.5f;
    const float sxs[4] = {-1.f, -1.f, 1.f, 1.f};
    const float sys[4] = {-1.f, 1.f, 1.f, -1.f};
    float minx = 1e30f, miny = 1e30f, maxx = -1e30f, maxy = -1e30f;
    #pragma unroll
    for (int k = 0; k < 4; ++k) {
        float cx = dx * sxs[k], cy = dy * sys[k];
        float px = cx * cc + cy * ss;
        float py = cx * (-ss) + cy * cc;
        px = px + xg; py = py + yg;
        minx = fminf(minx, px); maxx = fmaxf(maxx, px);
        miny = fminf(miny, py); maxy = fmaxf(maxy, py);
    }
    *areao = (maxx - minx) * (maxy - miny);
    return make_float4(minx, miny, maxx, maxy);
}

// decode + standup once per selected box
__global__ void k_decode(const u64* __restrict__ sel2, const float* __restrict__ boxp,
                         const float* __restrict__ anch, float4* __restrict__ bb,
                         float* __restrict__ area) {
    int r = blockIdx.x * blockDim.x + threadIdx.x;
    if (r >= KSEL) return;
    float b[7];
    decode_box(sel2[r], boxp, anch, b);
    float a;
    bb[r] = standup_box(b, &a);
    area[r] = a;
}

// 64x64 IoU mask tile; lower-triangle tiles (cb<rb) are never consumed -> zeros
__global__ __launch_bounds__(64) void k_mask(const float4* __restrict__ bb,
                                             const float* __restrict__ area,
                                             u64* __restrict__ mask) {
    int t = threadIdx.x;
    int rb = blockIdx.y, cb = blockIdx.x;
    int i = rb * 64 + t;
    if (cb < rb) { mask[(size_t)i * 64 + cb] = 0ull; return; }
    __shared__ float4 ob[64];
    __shared__ float oa[64];
    int jg0 = cb * 64;
    ob[t] = bb[jg0 + t];
    oa[t] = area[jg0 + t];
    __syncthreads();
    float4 m4 = bb[i];
    float ma = area[i];
    u64 bits = 0;
    for (int j = 0; j < 64; ++j) {
        int jg = jg0 + j;
        if (jg == i) continue;
        float4 o = ob[j];
        float ltx = fmaxf(m4.x, o.x), lty = fmaxf(m4.y, o.y);
        float rbx = fminf(m4.z, o.z), rby = fminf(m4.w, o.w);
        float w = fmaxf(rbx - ltx, 0.0f), h = fmaxf(rby - lty, 0.0f);
        float inter = w * h;
        float iou = inter / (ma + oa[j] - inter + 1e-8f);
        if (iou > 0.5f) bits |= (1ULL << j);
    }
    mask[(size_t)i * 64 + cb] = bits;
}

// one wave; lane l owns bits [l*64, l*64+64) of the availability bitmap.
// Window-64 greedy: 64 lowest available ranks per round; in-window suppression
// matrix via direct upper-triangle mask loads (lane j gathers column j);
// commit loop replicated on all lanes; rows loaded AFTER commit, independently.
__global__ __launch_bounds__(64) void k_serial(const u64* __restrict__ mask,
                                               u32* __restrict__ keep_list,
                                               u32* __restrict__ scal) {
    int lane = threadIdx.x;
    u32 nvt = scal[9];
    u32 nv = (nvt < (u32)KSEL) ? nvt : (u32)KSEL;
    int lo = lane * 64;
    u64 avail;
    if ((int)nv >= lo + 64) avail = ~0ull;
    else if ((int)nv <= lo) avail = 0ull;
    else avail = (((u64)1) << (nv - lo)) - 1ull;

    __shared__ int ls_cand[64];
    __shared__ u64 ls_m[64];
    int cnt = 0;
    for (;;) {
        // --- select first 64 available ranks ---
        u32 pc = (u32)__popcll(avail);
        u32 pre = pc;
        #pragma unroll
        for (int off = 1; off < 64; off <<= 1) {
            u32 y = __shfl_up(pre, (unsigned)off);
            if (lane >= off) pre += y;
        }
        u32 excl = pre - pc;
        ls_cand[lane] = -1;
        __syncthreads();
        if (pc && excl < 64u) {
            u64 a = avail;
            u32 o = excl;
            while (a && o < 64u) {
                int b = (int)__builtin_ctzll(a);
                a &= a - 1;
                ls_cand[o++] = lo + b;
            }
        }
        __syncthreads();
        int c[64];
        #pragma unroll
        for (int j = 0; j < 64; ++j) c[j] = ls_cand[j];
        if (c[0] < 0) break;
        // --- window matrix: lane j gathers "i suppresses j" bits for i<j ---
        u64 mm = 0;
        if (c[lane] >= 0) {
            int word = c[lane] >> 6;
            int sh = c[lane] & 63;
            #pragma unroll
            for (int i = 0; i < 64; ++i) {
                if (i < lane && c[i] >= 0) {
                    u64 v = mask[(size_t)c[i] * 64 + word];
                    mm |= ((v >> sh) & 1ull) << i;
                }
            }
        }
        ls_m[lane] = mm;
        __syncthreads();
        // --- ordered commit, replicated on all lanes ---
        u64 committed = 0;
        bool stop = false;
        #pragma unroll
        for (int j = 0; j < 64; ++j) {
            if (stop || c[j] < 0) continue;
            u64 mj = ls_m[j];
            if (mj & committed) continue;
            if (lane == 0 && cnt < POST) keep_list[cnt] = (u32)c[j];
            committed |= (1ull << j);
            cnt++;
            if (cnt >= POST) stop = true;
        }
        __syncthreads();
        // --- apply committed rows: 64 independent loads, OR-masked ---
        u64 acc = 0;
        #pragma unroll
        for (int j = 0; j < 64; ++j) {
            int cj = (c[j] >= 0) ? c[j] : c[0];
            u64 r = mask[(size_t)cj * 64 + lane];
            if ((committed >> j) & 1ull) acc |= r;
        }
        avail &= ~acc;
        #pragma unroll
        for (int j = 0; j < 64; ++j) {
            if (((committed >> j) & 1ull) && lane == (c[j] >> 6))
                avail &= ~(((u64)1) << (c[j] & 63));
        }
        if (stop) break;
    }
    if (lane == 0) scal[7] = (u32)(cnt < POST ? cnt : POST);
}

__global__ void k_final(const u32* __restrict__ scal, const u32* __restrict__ keep_list,
                        const u64* __restrict__ sel2, const float* __restrict__ boxp,
                        const float* __restrict__ anch, const float* __restrict__ cls,
                        const float* __restrict__ dirp, float* __restrict__ out) {
    int t = blockIdx.x * blockDim.x + threadIdx.x;
    if (t >= POST) return;
    u32 m = scal[7];
    float* ob = out;
    float* os = out + POST * 7;
    float* ol = os + POST;
    float* ov = ol + POST;
    if (t < (int)m) {
        u32 r = keep_list[t];
        u64 cp = sel2[r];
        u32 key = (u32)(cp >> 32);
        u32 i = ~((u32)(cp & 0xFFFFFFFFull));
        float b[7];
        decode_box(cp, boxp, anch, b);
        float d0 = dirp[(size_t)i * 2], d1 = dirp[(size_t)i * 2 + 1];
        int dl = (d1 > d0) ? 1 : 0;
        int pos = (b[6] > 0.0f) ? 1 : 0;
        if (pos ^ dl) b[6] = b[6] + 3.14159265358979323846f;
        for (int q = 0; q < 7; ++q) ob[(size_t)t * 7 + q] = b[q];
        os[t] = __uint_as_float(key);
        float s0 = 1.0f / (1.0f + expf(-cls[(size_t)i * 3]));
        float s1 = 1.0f / (1.0f + expf(-cls[(size_t)i * 3 + 1]));
        float s2 = 1.0f / (1.0f + expf(-cls[(size_t)i * 3 + 2]));
        int lab = 0; float best = s0;
        if (s1 > best) { lab = 1; best = s1; }
        if (s2 > best) { lab = 2; }
        ol[t] = (float)lab;
        ov[t] = 1.0f;
    } else {
        for (int q = 0; q < 7; ++q) ob[(size_t)t * 7 + q] = 0.0f;
        os[t] = 0.0f;
        ol[t] = -1.0f;
        ov[t] = 0.0f;
    }
}

extern "C" void kernel_launch(void* const* d_in, const int* in_sizes, int n_in,
                              void* d_out, int out_size, void* d_ws, size_t ws_size,
                              hipStream_t stream) {
    const float* box_preds = (const float*)d_in[0];
    const float* cls_preds = (const float*)d_in[1];
    const float* dir_preds = (const float*)d_in[2];
    const float* anchors   = (const float*)d_in[3];
    float* out = (float*)d_out;

    unsigned char* w = (unsigned char*)d_ws;
    size_t off = 0;
    auto nxt = [&](size_t bytes) -> void* {
        void* p = (void*)(w + off);
        off = (off + bytes + 255) & ~(size_t)255;
        return p;
    };
    // memset region (contiguous): hist1 | scal | sel2 | rank
    u32* hist1     = (u32*)nxt(H1BINS * 4);            //  4096 B
    u32* scal      = (u32*)nxt(64 * 4);                //   256 B
    u64* sel2      = (u64*)nxt((size_t)KSEL * 8);      // 32768 B
    u32* rank      = (u32*)nxt((size_t)CANDCAP * 4);   // 65536 B
    u64* cand      = (u64*)nxt((size_t)CANDCAP * 8);
    u64* mask      = (u64*)nxt((size_t)KSEL * 64 * 8);
    u32* keep_list = (u32*)nxt(512 * 4);
    float4* bb     = (float4*)nxt((size_t)KSEL * 16);
    float* area    = (float*)nxt((size_t)KSEL * 4);
    u32* keys      = (u32*)nxt((size_t)N_ANCH * 4);

    hipMemsetAsync(hist1, 0,
                   (size_t)H1BINS * 4 + 256 + (size_t)KSEL * 8 + (size_t)CANDCAP * 4,
                   stream);

    k_keys<<<(NQUAD + 1023) / 1024, 1024, 0, stream>>>((const float4*)cls_preds,
                                                       (uint4*)keys, hist1);
    k_scan1<<<1, 1024, 0, stream>>>(hist1, scal);
    k_compact<<<(NQUAD + 255) / 256, 256, 0, stream>>>((const uint4*)keys, scal, cand);
    dim3 rg(CANDCAP / 256, CANDCAP / 512);
    k_rankpart<<<rg, 256, 0, stream>>>(scal, cand, rank);
    k_scatter<<<CANDCAP / 256, 256, 0, stream>>>(scal, cand, rank, sel2);
    k_decode<<<KSEL / 256, 256, 0, stream>>>(sel2, box_preds, anchors, bb, area);
    dim3 mg(64, 64);
    k_mask<<<mg, 64, 0, stream>>>(bb, area, mask);
    k_serial<<<1, 64, 0, stream>>>(mask, keep_list, scal);
    k_final<<<2, 256, 0, stream>>>(scal, keep_list, sel2, box_preds, anchors, cls_preds, dir_preds, out);
}

// Round 7
// 138.282 us; speedup vs baseline: 2.2998x; 2.2998x over previous
//
#include <hip/hip_runtime.h>

#pragma clang fp contract(off)

#define N_ANCH 321408
#define NQUAD (N_ANCH / 4)
#define KSEL 4096
#define POST 300
#define H1BINS 1024
#define H1BASE 0x3D40u   // remap: bin = (k>>16) - H1BASE + 1 ; bin 0 = invalid (k==0)
#define CANDCAP 16384
#define W 32             // NMS window width; state must stay register-resident

typedef unsigned int u32;
typedef unsigned long long u64;

__device__ __forceinline__ u32 key_of(float m) {
    float s = 1.0f / (1.0f + expf(-m));
    return (s >= 0.05f) ? __float_as_uint(s) : 0u;
}

// ---------------- scoring (vectorized 4 anchors/thread) + coarse histogram ----------------
__global__ __launch_bounds__(1024) void k_keys(const float4* __restrict__ cls4,
                                               uint4* __restrict__ keys4,
                                               u32* __restrict__ hist) {
    __shared__ u32 h0[H1BINS], h1[H1BINS];
    int t = threadIdx.x;
    h0[t] = 0; h1[t] = 0;
    __syncthreads();
    int q = blockIdx.x * 1024 + t;
    if (q < NQUAD) {
        float4 a = cls4[q * 3], b = cls4[q * 3 + 1], d = cls4[q * 3 + 2];
        u32 k0 = key_of(fmaxf(a.x, fmaxf(a.y, a.z)));
        u32 k1 = key_of(fmaxf(a.w, fmaxf(b.x, b.y)));
        u32 k2 = key_of(fmaxf(b.z, fmaxf(b.w, d.x)));
        u32 k3 = key_of(fmaxf(d.y, fmaxf(d.z, d.w)));
        keys4[q] = make_uint4(k0, k1, k2, k3);
        u32* hp = (t & 1) ? h1 : h0;
        atomicAdd(&hp[k0 ? ((k0 >> 16) - H1BASE + 1u) : 0u], 1u);
        atomicAdd(&hp[k1 ? ((k1 >> 16) - H1BASE + 1u) : 0u], 1u);
        atomicAdd(&hp[k2 ? ((k2 >> 16) - H1BASE + 1u) : 0u], 1u);
        atomicAdd(&hp[k3 ? ((k3 >> 16) - H1BASE + 1u) : 0u], 1u);
    }
    __syncthreads();
    u32 c = h0[t] + h1[t];
    if (c) atomicAdd(&hist[t], c);
}

// scan 1024 coarse bins from the top: crossing bin + total valid count
__global__ __launch_bounds__(1024) void k_scan1(const u32* __restrict__ hist, u32* scal) {
    __shared__ u32 sh[1024];
    int t = threadIdx.x;
    int b = 1023 - t;                 // descending bins
    u32 s = hist[b];
    sh[t] = s;
    __syncthreads();
    for (int off = 1; off < 1024; off <<= 1) {
        u32 x = sh[t];
        u32 y = (t >= off) ? sh[t - off] : 0u;
        __syncthreads();
        sh[t] = x + y;
        __syncthreads();
    }
    u32 incl = sh[t];
    u32 excl = incl - s;
    if (excl < 4096u && incl >= 4096u) {
        scal[8] = (b > 0) ? (u32)(b - 1) + H1BASE : 0u;   // actual upper-16 of crossing bin
    }
    if (t == 1023) scal[9] = incl - s;                    // total valid (minus bin 0)
}

// all candidates in bins >= crossing bin; wave-aggregated atomic, vectorized reads
__global__ __launch_bounds__(256) void k_compact(const uint4* __restrict__ keys4,
                                                 u32* scal, u64* __restrict__ cand) {
    int q = blockIdx.x * 256 + threadIdx.x;
    bool act = q < NQUAD;
    uint4 kv = act ? keys4[q] : make_uint4(0, 0, 0, 0);
    u32 thr16 = scal[8];
    int lane = threadIdx.x & 63;
    u32 i0 = (u32)q * 4u;
    bool p0 = kv.x && (kv.x >> 16) >= thr16;
    bool p1 = kv.y && (kv.y >> 16) >= thr16;
    bool p2 = kv.z && (kv.z >> 16) >= thr16;
    bool p3 = kv.w && (kv.w >> 16) >= thr16;
    u64 b0 = __ballot(p0), b1 = __ballot(p1), b2 = __ballot(p2), b3 = __ballot(p3);
    u32 n0 = (u32)__popcll(b0), n1 = (u32)__popcll(b1), n2 = (u32)__popcll(b2);
    u32 nw = n0 + n1 + n2 + (u32)__popcll(b3);
    u32 base = 0;
    if (lane == 0 && nw) base = atomicAdd(&scal[5], nw);
    base = (u32)__shfl((int)base, 0);
    u64 lt = (lane == 0) ? 0ull : (~0ull >> (64 - lane));
    if (p0) { u32 p = base + (u32)__popcll(b0 & lt);
              if (p < CANDCAP) cand[p] = (((u64)kv.x) << 32) | (u32)(~(i0 + 0)); }
    if (p1) { u32 p = base + n0 + (u32)__popcll(b1 & lt);
              if (p < CANDCAP) cand[p] = (((u64)kv.y) << 32) | (u32)(~(i0 + 1)); }
    if (p2) { u32 p = base + n0 + n1 + (u32)__popcll(b2 & lt);
              if (p < CANDCAP) cand[p] = (((u64)kv.z) << 32) | (u32)(~(i0 + 2)); }
    if (p3) { u32 p = base + n0 + n1 + n2 + (u32)__popcll(b3 & lt);
              if (p < CANDCAP) cand[p] = (((u64)kv.w) << 32) | (u32)(~(i0 + 3)); }
}

// 2D partial rank-by-counting
__global__ __launch_bounds__(256) void k_rankpart(const u32* __restrict__ scal,
                                                  const u64* __restrict__ cand,
                                                  u32* __restrict__ rank) {
    __shared__ u64 ch[512];
    u32 nc = scal[5]; if (nc > CANDCAP) nc = CANDCAP;
    u32 cb = blockIdx.x * 256u;
    u32 jb = blockIdx.y * 512u;
    if (cb >= nc || jb >= nc) return;
    u32 t = threadIdx.x;
    for (u32 j = t; j < 512u; j += 256u)
        ch[j] = (jb + j < nc) ? cand[jb + j] : 0ull;
    __syncthreads();
    u32 me = cb + t;
    u64 mine = (me < nc) ? cand[me] : ~0ull;
    u32 r = 0;
    #pragma unroll 8
    for (int j = 0; j < 512; ++j) r += (ch[j] > mine) ? 1u : 0u;
    if (me < nc && r) atomicAdd(&rank[me], r);
}

__global__ void k_scatter(const u32* __restrict__ scal, const u64* __restrict__ cand,
                          const u32* __restrict__ rank, u64* __restrict__ sorted) {
    u32 nc = scal[5]; if (nc > CANDCAP) nc = CANDCAP;
    u32 t = blockIdx.x * 256u + threadIdx.x;
    if (t < nc) {
        u32 r = rank[t];
        if (r < (u32)KSEL) sorted[r] = cand[t];
    }
}

// ---------------- decode helpers ----------
__device__ __forceinline__ void decode_box(u64 cpack, const float* __restrict__ boxp,
                                           const float* __restrict__ anch, float b[7]) {
    u32 key = (u32)(cpack >> 32);
    u32 idx = ~((u32)(cpack & 0xFFFFFFFFull));
    if (key == 0u) idx = 0u;
    const float* a7 = anch + (size_t)idx * 7;
    const float* t7 = boxp + (size_t)idx * 7;
    float xa = a7[0], ya = a7[1], za = a7[2], wa = a7[3], la = a7[4], ha = a7[5], ra = a7[6];
    float xt = t7[0], yt = t7[1], zt = t7[2], wt = t7[3], lt_ = t7[4], ht = t7[5], rt = t7[6];
    za = za + ha * 0.5f;
    float diag = sqrtf(la * la + wa * wa);
    float xg = xt * diag + xa;
    float yg = yt * diag + ya;
    float zg = zt * ha + za;
    float lg = expf(lt_) * la;
    float wg = expf(wt) * wa;
    float hg = expf(ht) * ha;
    float rg = rt + ra;
    zg = zg - hg * 0.5f;
    b[0] = xg; b[1] = yg; b[2] = zg; b[3] = wg; b[4] = lg; b[5] = hg; b[6] = rg;
}

__device__ __forceinline__ float4 standup_box(const float b[7], float* areao) {
    float xg = b[0], yg = b[1], wg = b[3], lg = b[4], rg = b[6];
    float cc = cosf(rg), ss = sinf(rg);
    float dx = wg * 0.5f, dy = lg * 0.5f;
    const float sxs[4] = {-1.f, -1.f, 1.f, 1.f};
    const float sys[4] = {-1.f, 1.f, 1.f, -1.f};
    float minx = 1e30f, miny = 1e30f, maxx = -1e30f, maxy = -1e30f;
    #pragma unroll
    for (int k = 0; k < 4; ++k) {
        float cx = dx * sxs[k], cy = dy * sys[k];
        float px = cx * cc + cy * ss;
        float py = cx * (-ss) + cy * cc;
        px = px + xg; py = py + yg;
        minx = fminf(minx, px); maxx = fmaxf(maxx, px);
        miny = fminf(miny, py); maxy = fmaxf(maxy, py);
    }
    *areao = (maxx - minx) * (maxy - miny);
    return make_float4(minx, miny, maxx, maxy);
}

// decode + standup once per selected box
__global__ void k_decode(const u64* __restrict__ sel2, const float* __restrict__ boxp,
                         const float* __restrict__ anch, float4* __restrict__ bb,
                         float* __restrict__ area) {
    int r = blockIdx.x * blockDim.x + threadIdx.x;
    if (r >= KSEL) return;
    float b[7];
    decode_box(sel2[r], boxp, anch, b);
    float a;
    bb[r] = standup_box(b, &a);
    area[r] = a;
}

// 64x64 IoU mask tile; lower-triangle tiles (cb<rb) are never consumed -> zeros
__global__ __launch_bounds__(64) void k_mask(const float4* __restrict__ bb,
                                             const float* __restrict__ area,
                                             u64* __restrict__ mask) {
    int t = threadIdx.x;
    int rb = blockIdx.y, cb = blockIdx.x;
    int i = rb * 64 + t;
    if (cb < rb) { mask[(size_t)i * 64 + cb] = 0ull; return; }
    __shared__ float4 ob[64];
    __shared__ float oa[64];
    int jg0 = cb * 64;
    ob[t] = bb[jg0 + t];
    oa[t] = area[jg0 + t];
    __syncthreads();
    float4 m4 = bb[i];
    float ma = area[i];
    u64 bits = 0;
    for (int j = 0; j < 64; ++j) {
        int jg = jg0 + j;
        if (jg == i) continue;
        float4 o = ob[j];
        float ltx = fmaxf(m4.x, o.x), lty = fmaxf(m4.y, o.y);
        float rbx = fminf(m4.z, o.z), rby = fminf(m4.w, o.w);
        float w = fmaxf(rbx - ltx, 0.0f), h = fmaxf(rby - lty, 0.0f);
        float inter = w * h;
        float iou = inter / (ma + oa[j] - inter + 1e-8f);
        if (iou > 0.5f) bits |= (1ULL << j);
    }
    mask[(size_t)i * 64 + cb] = bits;
}

__device__ __forceinline__ u64 shfl_u64(u64 v, int src) {
    int lo = __shfl((int)(u32)(v & 0xFFFFFFFFull), src);
    int hi = __shfl((int)(u32)(v >> 32), src);
    return (((u64)(u32)hi) << 32) | (u32)lo;
}

// one wave; lane l owns bits [l*64, l*64+64) of the availability bitmap.
// Window-32 greedy (register-resident R5 pattern): 32 lowest available ranks via
// one prefix-sum; 32 rows loaded in parallel; window matrix via bpermute gather;
// register-copied commit loop; no restarts.
__global__ __launch_bounds__(64) void k_serial(const u64* __restrict__ mask,
                                               u32* __restrict__ keep_list,
                                               u32* __restrict__ scal) {
    int lane = threadIdx.x;
    u32 nvt = scal[9];
    u32 nv = (nvt < (u32)KSEL) ? nvt : (u32)KSEL;
    int lo = lane * 64;
    u64 avail;
    if ((int)nv >= lo + 64) avail = ~0ull;
    else if ((int)nv <= lo) avail = 0ull;
    else avail = (((u64)1) << (nv - lo)) - 1ull;

    __shared__ int ls_cand[W];
    __shared__ u32 ls_m[W];
    int cnt = 0;
    for (;;) {
        // --- select first W available ranks ---
        u32 pc = (u32)__popcll(avail);
        u32 pre = pc;
        #pragma unroll
        for (int off = 1; off < 64; off <<= 1) {
            u32 y = __shfl_up(pre, (unsigned)off);
            if (lane >= off) pre += y;
        }
        u32 excl = pre - pc;
        if (lane < W) { ls_cand[lane] = -1; ls_m[lane] = 0u; }
        __syncthreads();
        if (pc && excl < (u32)W) {
            u64 a = avail;
            u32 o = excl;
            while (a && o < (u32)W) {
                int b = (int)__builtin_ctzll(a);
                a &= a - 1;
                ls_cand[o++] = lo + b;
            }
        }
        __syncthreads();
        int c[W];
        #pragma unroll
        for (int j = 0; j < W; ++j) c[j] = ls_cand[j];
        if (c[0] < 0) break;
        // --- fetch W rows in parallel (word `lane` of each committed-candidate row) ---
        u64 rows[W];
        #pragma unroll
        for (int j = 0; j < W; ++j)
            rows[j] = (c[j] >= 0) ? mask[(size_t)c[j] * 64 + lane] : 0ull;
        // --- lane j<W gathers its candidate's bit from every row (pipelined bpermutes)
        int src = (lane < W && c[lane] >= 0) ? (c[lane] >> 6) : 0;
        int sh  = (lane < W && c[lane] >= 0) ? (c[lane] & 63) : 0;
        u32 m = 0;
        #pragma unroll
        for (int jp = 0; jp < W; ++jp) {
            u64 v = shfl_u64(rows[jp], src);
            m |= (u32)((v >> sh) & 1ull) << jp;
        }
        if (lane < W && c[lane] >= 0) ls_m[lane] = m;
        __syncthreads();
        u32 mm[W];
        #pragma unroll
        for (int j = 0; j < W; ++j) mm[j] = ls_m[j];
        // --- branchless ordered commit, replicated on all lanes ---
        u32 committed = 0;
        bool stop = false;
        #pragma unroll
        for (int j = 0; j < W; ++j) {
            if (stop) continue;
            if (c[j] < 0) continue;
            if (mm[j] & committed) continue;     // suppressed by earlier commit in window
            if (lane == 0 && cnt < POST) keep_list[cnt] = (u32)c[j];
            committed |= (1u << j);
            cnt++;
            if (cnt >= POST) stop = true;
        }
        // --- apply committed rows to the global availability bitmap ---
        #pragma unroll
        for (int j = 0; j < W; ++j) {
            if ((committed >> j) & 1u) {
                avail &= ~rows[j];
                if (lane == (c[j] >> 6)) avail &= ~(((u64)1) << (c[j] & 63));
            }
        }
        if (stop) break;
    }
    if (lane == 0) scal[7] = (u32)(cnt < POST ? cnt : POST);
}

__global__ void k_final(const u32* __restrict__ scal, const u32* __restrict__ keep_list,
                        const u64* __restrict__ sel2, const float* __restrict__ boxp,
                        const float* __restrict__ anch, const float* __restrict__ cls,
                        const float* __restrict__ dirp, float* __restrict__ out) {
    int t = blockIdx.x * blockDim.x + threadIdx.x;
    if (t >= POST) return;
    u32 m = scal[7];
    float* ob = out;
    float* os = out + POST * 7;
    float* ol = os + POST;
    float* ov = ol + POST;
    if (t < (int)m) {
        u32 r = keep_list[t];
        u64 cp = sel2[r];
        u32 key = (u32)(cp >> 32);
        u32 i = ~((u32)(cp & 0xFFFFFFFFull));
        float b[7];
        decode_box(cp, boxp, anch, b);
        float d0 = dirp[(size_t)i * 2], d1 = dirp[(size_t)i * 2 + 1];
        int dl = (d1 > d0) ? 1 : 0;
        int pos = (b[6] > 0.0f) ? 1 : 0;
        if (pos ^ dl) b[6] = b[6] + 3.14159265358979323846f;
        for (int q = 0; q < 7; ++q) ob[(size_t)t * 7 + q] = b[q];
        os[t] = __uint_as_float(key);
        float s0 = 1.0f / (1.0f + expf(-cls[(size_t)i * 3]));
        float s1 = 1.0f / (1.0f + expf(-cls[(size_t)i * 3 + 1]));
        float s2 = 1.0f / (1.0f + expf(-cls[(size_t)i * 3 + 2]));
        int lab = 0; float best = s0;
        if (s1 > best) { lab = 1; best = s1; }
        if (s2 > best) { lab = 2; }
        ol[t] = (float)lab;
        ov[t] = 1.0f;
    } else {
        for (int q = 0; q < 7; ++q) ob[(size_t)t * 7 + q] = 0.0f;
        os[t] = 0.0f;
        ol[t] = -1.0f;
        ov[t] = 0.0f;
    }
}

extern "C" void kernel_launch(void* const* d_in, const int* in_sizes, int n_in,
                              void* d_out, int out_size, void* d_ws, size_t ws_size,
                              hipStream_t stream) {
    const float* box_preds = (const float*)d_in[0];
    const float* cls_preds = (const float*)d_in[1];
    const float* dir_preds = (const float*)d_in[2];
    const float* anchors   = (const float*)d_in[3];
    float* out = (float*)d_out;

    unsigned char* w = (unsigned char*)d_ws;
    size_t off = 0;
    auto nxt = [&](size_t bytes) -> void* {
        void* p = (void*)(w + off);
        off = (off + bytes + 255) & ~(size_t)255;
        return p;
    };
    // memset region (contiguous): hist1 | scal | sel2 | rank
    u32* hist1     = (u32*)nxt(H1BINS * 4);            //  4096 B
    u32* scal      = (u32*)nxt(64 * 4);                //   256 B
    u64* sel2      = (u64*)nxt((size_t)KSEL * 8);      // 32768 B
    u32* rank      = (u32*)nxt((size_t)CANDCAP * 4);   // 65536 B
    u64* cand      = (u64*)nxt((size_t)CANDCAP * 8);
    u64* mask      = (u64*)nxt((size_t)KSEL * 64 * 8);
    u32* keep_list = (u32*)nxt(512 * 4);
    float4* bb     = (float4*)nxt((size_t)KSEL * 16);
    float* area    = (float*)nxt((size_t)KSEL * 4);
    u32* keys      = (u32*)nxt((size_t)N_ANCH * 4);

    hipMemsetAsync(hist1, 0,
                   (size_t)H1BINS * 4 + 256 + (size_t)KSEL * 8 + (size_t)CANDCAP * 4,
                   stream);

    k_keys<<<(NQUAD + 1023) / 1024, 1024, 0, stream>>>((const float4*)cls_preds,
                                                       (uint4*)keys, hist1);
    k_scan1<<<1, 1024, 0, stream>>>(hist1, scal);
    k_compact<<<(NQUAD + 255) / 256, 256, 0, stream>>>((const uint4*)keys, scal, cand);
    dim3 rg(CANDCAP / 256, CANDCAP / 512);
    k_rankpart<<<rg, 256, 0, stream>>>(scal, cand, rank);
    k_scatter<<<CANDCAP / 256, 256, 0, stream>>>(scal, cand, rank, sel2);
    k_decode<<<KSEL / 256, 256, 0, stream>>>(sel2, box_preds, anchors, bb, area);
    dim3 mg(64, 64);
    k_mask<<<mg, 64, 0, stream>>>(bb, area, mask);
    k_serial<<<1, 64, 0, stream>>>(mask, keep_list, scal);
    k_final<<<2, 256, 0, stream>>>(scal, keep_list, sel2, box_preds, anchors, cls_preds, dir_preds, out);
}